// Round 10
// baseline (309.163 us; speedup 1.0000x reference)
//
#include <hip/hip_runtime.h>
#include <hip/hip_bf16.h>
#include <math.h>

#define N 8192
#define D 1024
#define BM 256
#define BK 64
#define NQUART 64                       // 16 tiles (ti=31, tj=0..15) x 4 quadrants
#define NFULL 512                       // 528 - 16 quartered tiles
#define NBLK (NQUART + NFULL)           // 576
#define ITERS 8                         // full path: 16 K-tiles / 2 per iter

typedef __bf16 bf16_t;
typedef bf16_t bf16x4 __attribute__((ext_vector_type(4)));
typedef bf16_t bf16x8 __attribute__((ext_vector_type(8)));
typedef float f32x4 __attribute__((ext_vector_type(4)));

// ---------------------------------------------------------------------------
// Kernel 1: L2-normalize each row, cast to bf16. Wave-per-row. Also zeroes
// sumExp/posSum and the gemm completion counter.
// ---------------------------------------------------------------------------
__global__ __launch_bounds__(256) void norm_cast(const float* __restrict__ in,
                                                 bf16_t* __restrict__ out,
                                                 float* __restrict__ sumExp,
                                                 float* __restrict__ posSum,
                                                 int* __restrict__ cnt) {
    const int wave = threadIdx.x >> 6, lane = threadIdx.x & 63;
    const int row  = blockIdx.x * 4 + wave;
    if (blockIdx.x == 0 && threadIdx.x == 0) *cnt = 0;
    const float4* src = (const float4*)(in + (size_t)row * D);
    float4 v[4];
    float ss = 0.f;
    #pragma unroll
    for (int i = 0; i < 4; ++i) {
        v[i] = src[lane + 64 * i];
        ss += v[i].x * v[i].x + v[i].y * v[i].y + v[i].z * v[i].z + v[i].w * v[i].w;
    }
    #pragma unroll
    for (int off = 32; off >= 1; off >>= 1) ss += __shfl_xor(ss, off, 64);
    const float scale = 1.0f / fmaxf(sqrtf(ss), 1e-12f);
    bf16x4* dst = (bf16x4*)(out + (size_t)row * D);
    #pragma unroll
    for (int i = 0; i < 4; ++i) {
        bf16x4 o;
        o[0] = (bf16_t)(v[i].x * scale);
        o[1] = (bf16_t)(v[i].y * scale);
        o[2] = (bf16_t)(v[i].z * scale);
        o[3] = (bf16_t)(v[i].w * scale);
        dst[lane + 64 * i] = o;
    }
    if (lane == 0) { sumExp[row] = 0.f; posSum[row] = 0.f; }
}

// ---------------------------------------------------------------------------
// Kernel 2: fused symmetric  C = E·E^T / T -> exp -> masked row+col sums,
// PLUS last-block finalize (log-ratio mean) -> out[0].
// R10 deltas vs R9: (a) quarter path rebuilt on a 3-slot LDS ring with one
// counted vmcnt(4) per K-step (full K-step of HBM latency slack) instead of
// per-step vmcnt(0) drains; (b) finalize kernel merged via done-counter.
// Full 256^2 8-phase path byte-identical to R9.
// ---------------------------------------------------------------------------
__global__ __launch_bounds__(512, 2) void gemm_fused(const bf16_t* __restrict__ E,
                                                     const int* __restrict__ labels,
                                                     float* __restrict__ sumExp,
                                                     float* __restrict__ posSum,
                                                     float* __restrict__ out,
                                                     int* __restrict__ cnt) {
    __shared__ bf16_t As[2][2][128 * 64];   // 64 KB (also: quarter-path 3-slot ring / tail scratch)
    __shared__ bf16_t Bs[2][2][128 * 64];   // 64 KB  (total 131072 B)

    const int tid  = threadIdx.x;
    const int wave = tid >> 6;
    const int lane = tid & 63;
    const int lr   = lane & 15;
    const int q    = lane >> 4;
    const float invT = 1.0f / 0.07f;

    // swizzled frag-read units (identical formula both paths; 128B LDS rows)
    const int su0 = ((0 + q) ^ (lane & 7)) * 16;     // k = 0
    const int su1 = ((4 + q) ^ (lane & 7)) * 16;     // k = 1

    #define PHASE_MID() do {                                                             \
        __builtin_amdgcn_s_barrier();                                                    \
        asm volatile("s_waitcnt lgkmcnt(0)");                                            \
        __builtin_amdgcn_sched_barrier(0);                                               \
        __builtin_amdgcn_s_setprio(1);                                                   \
    } while (0)
    #define PHASE_END() do {                                                             \
        __builtin_amdgcn_s_setprio(0);                                                   \
        __builtin_amdgcn_s_barrier();                                                    \
    } while (0)

    if (blockIdx.x < NQUART) {
        // ===================================================================
        // QUARTER PATH: 128x128 tile, full K. 3-slot ring (16 KB/slot/operand)
        // carved from As/Bs; stage 2 K-tiles ahead, one counted vmcnt(4) per
        // K-step. All quarters strictly below the diagonal.
        // ===================================================================
        const int qb = ((int)blockIdx.x & 7) * 8 + ((int)blockIdx.x >> 3);
        const int p  = qb >> 2, qd = qb & 3;
        const int rowStart = 31 * BM + (qd >> 1) * 128;
        const int colStart = p * BM + (qd & 1) * 128;
        const int wm2 = wave >> 2;      // 0..1 : 64-row half
        const int wn2 = wave & 3;       // 0..3 : 32-col strip
        char* Aflat = (char*)&As[0][0][0];
        char* Bflat = (char*)&Bs[0][0][0];

        f32x4 acc[4][2];
        #pragma unroll
        for (int m = 0; m < 4; ++m) { acc[m][0] = {0,0,0,0}; acc[m][1] = {0,0,0,0}; }

        const int r0  = tid >> 3;                    // 0..63
        const int lu0 = (tid & 7) ^ (r0 & 7);
        const char* gA = (const char*)(E + (size_t)rowStart * D) + (size_t)r0 * (D * 2) + lu0 * 16;
        const char* gB = (const char*)(E + (size_t)colStart * D) + (size_t)r0 * (D * 2) + lu0 * 16;

        #define QSTAGE(slot, kb) do {                                                    \
            const char* ga_ = gA + (kb);                                                 \
            const char* gb_ = gB + (kb);                                                 \
            char* la_ = Aflat + (slot) * 16384 + wave * 1024;                            \
            char* lb_ = Bflat + (slot) * 16384 + wave * 1024;                            \
            __builtin_amdgcn_global_load_lds((const __attribute__((address_space(1))) void*)ga_, \
                (__attribute__((address_space(3))) void*)la_, 16, 0, 0);                 \
            __builtin_amdgcn_global_load_lds(                                            \
                (const __attribute__((address_space(1))) void*)(ga_ + 64 * 2048),        \
                (__attribute__((address_space(3))) void*)(la_ + 8192), 16, 0, 0);        \
            __builtin_amdgcn_global_load_lds((const __attribute__((address_space(1))) void*)gb_, \
                (__attribute__((address_space(3))) void*)lb_, 16, 0, 0);                 \
            __builtin_amdgcn_global_load_lds(                                            \
                (const __attribute__((address_space(1))) void*)(gb_ + 64 * 2048),        \
                (__attribute__((address_space(3))) void*)(lb_ + 8192), 16, 0, 0);        \
        } while (0)

        bf16x8 qa[4], qbf[2];
        #define QLD(SU, slot) do {                                                       \
            const char* aB_ = Aflat + (slot) * 16384 + (wm2 * 64 + lr) * 128 + (SU);     \
            const char* bB_ = Bflat + (slot) * 16384 + (wn2 * 32 + lr) * 128 + (SU);     \
            _Pragma("unroll")                                                            \
            for (int m_ = 0; m_ < 4; ++m_)                                               \
                qa[m_] = *(const bf16x8*)(aB_ + m_ * 2048);                              \
            qbf[0] = *(const bf16x8*)(bB_);                                              \
            qbf[1] = *(const bf16x8*)(bB_ + 2048);                                       \
        } while (0)
        #define QMFMA() do {                                                             \
            _Pragma("unroll")                                                            \
            for (int m_ = 0; m_ < 4; ++m_) {                                             \
                _Pragma("unroll")                                                        \
                for (int n_ = 0; n_ < 2; ++n_)                                           \
                    acc[m_][n_] = __builtin_amdgcn_mfma_f32_16x16x32_bf16(               \
                        qa[m_], qbf[n_], acc[m_][n_], 0, 0, 0);                          \
            }                                                                            \
        } while (0)

        // prologue: stage K-tiles 0,1 (8 gloads); vmcnt(4) -> tile 0 landed,
        // tile 1 (4 loads) in flight.
        QSTAGE(0, 0);
        QSTAGE(1, 128);
        asm volatile("s_waitcnt vmcnt(4)" ::: "memory");
        __builtin_amdgcn_sched_barrier(0);
        __builtin_amdgcn_s_barrier();

        #pragma unroll 1
        for (int it = 0; it < 16; ++it) {
            const int slot = it % 3;
            // ph1: k0 frags | stage tile it+2 into slot (it+2)%3
            //   (that slot was read in iter it-1; reads fenced by its barrier)
            QLD(su0, slot);
            if (it < 14) QSTAGE((it + 2) % 3, (it + 2) * 128);
            PHASE_MID();
            QMFMA();
            PHASE_END();
            // ph2: k1 frags | counted wait: drain tile it+1 (oldest 4),
            //   keep tile it+2 in flight (a full K-step of slack)
            QLD(su1, slot);
            if (it < 14) asm volatile("s_waitcnt vmcnt(4)" ::: "memory");
            else         asm volatile("s_waitcnt vmcnt(0)" ::: "memory");
            __builtin_amdgcn_sched_barrier(0);
            PHASE_MID();
            QMFMA();
            PHASE_END();
        }

        // epilogue (always off-diagonal, gi != gj guaranteed)
        int lc[2];
        lc[0] = labels[colStart + wn2 * 32 + lr];
        lc[1] = labels[colStart + wn2 * 32 + 16 + lr];
        float colAll[2] = {0.f, 0.f}, colPos[2] = {0.f, 0.f};
        #pragma unroll
        for (int m = 0; m < 4; ++m) {
            #pragma unroll
            for (int e = 0; e < 4; ++e) {
                const int gi = rowStart + wm2 * 64 + m * 16 + q * 4 + e;
                const int li = labels[gi];
                float s_all = 0.f, s_pos = 0.f;
                #pragma unroll
                for (int n = 0; n < 2; ++n) {
                    const float v = __expf(acc[m][n][e] * invT);
                    const bool same = (lc[n] == li);
                    s_all += v;
                    if (same) s_pos += v;
                    colAll[n] += v;
                    if (same) colPos[n] += v;
                }
                #pragma unroll
                for (int off = 1; off < 16; off <<= 1) {
                    s_all += __shfl_xor(s_all, off, 64);
                    s_pos += __shfl_xor(s_pos, off, 64);
                }
                if (lr == 0) {
                    atomicAdd(&sumExp[gi], s_all);
                    atomicAdd(&posSum[gi], s_pos);
                }
            }
        }
        #pragma unroll
        for (int n = 0; n < 2; ++n) {
            float a = colAll[n], pp = colPos[n];
            a += __shfl_xor(a, 16, 64);  a += __shfl_xor(a, 32, 64);
            pp += __shfl_xor(pp, 16, 64); pp += __shfl_xor(pp, 32, 64);
            if (q == 0) {
                const int gj = colStart + wn2 * 32 + n * 16 + lr;
                atomicAdd(&sumExp[gj], a);
                atomicAdd(&posSum[gj], pp);
            }
        }
    } else {
    // =======================================================================
    // FULL PATH: R2's verified 256^2 / BK=64 / 8-phase kernel, unchanged.
    // =======================================================================
    const int f0 = (int)blockIdx.x - NQUART;
    const int f  = (f0 & 7) * (NFULL / 8) + (f0 >> 3);     // XCD swizzle, 512%8==0
    const int b  = (f < 496) ? f : f + 16;                 // skip tiles 496..511

    int ti = (int)((sqrtf(8.0f * (float)b + 1.0f) - 1.0f) * 0.5f);
    while ((ti + 1) * (ti + 2) / 2 <= b) ++ti;
    while (ti * (ti + 1) / 2 > b) --ti;
    const int tj = b - ti * (ti + 1) / 2;
    const bool isDiag = (ti == tj);

    const int wm   = wave >> 2;     // 0..1 : row half
    const int wn   = wave & 3;      // 0..3 : 64-col strip
    const int rowStart = ti * BM;
    const int colStart = tj * BM;

    f32x4 acc[8][4];
    #pragma unroll
    for (int m = 0; m < 8; ++m)
        #pragma unroll
        for (int n = 0; n < 4; ++n) acc[m][n] = {0.f, 0.f, 0.f, 0.f};

    const int r0  = tid >> 3;                    // 0..63 (second load adds 64 rows)
    const int lu0 = (tid & 7) ^ (r0 & 7);
    const char* gA = (const char*)(E + (size_t)rowStart * D) + (size_t)r0 * (D * 2) + lu0 * 16;
    const char* gB = (const char*)(E + (size_t)colStart * D) + (size_t)r0 * (D * 2) + lu0 * 16;

    #define STAGE_A(buf, h, kb) do {                                                     \
        const char* g0_ = gA + (size_t)(h) * (128 * 2048) + (kb);                        \
        char* l0_ = (char*)&As[buf][h][0] + wave * 1024;                                 \
        __builtin_amdgcn_global_load_lds((const __attribute__((address_space(1))) void*)g0_, \
            (__attribute__((address_space(3))) void*)l0_, 16, 0, 0);                     \
        __builtin_amdgcn_global_load_lds(                                                \
            (const __attribute__((address_space(1))) void*)(g0_ + 64 * 2048),            \
            (__attribute__((address_space(3))) void*)(l0_ + 8192), 16, 0, 0);            \
    } while (0)
    #define STAGE_B(buf, h, kb) do {                                                     \
        const char* g0_ = gB + (size_t)(h) * (128 * 2048) + (kb);                        \
        char* l0_ = (char*)&Bs[buf][h][0] + wave * 1024;                                 \
        __builtin_amdgcn_global_load_lds((const __attribute__((address_space(1))) void*)g0_, \
            (__attribute__((address_space(3))) void*)l0_, 16, 0, 0);                     \
        __builtin_amdgcn_global_load_lds(                                                \
            (const __attribute__((address_space(1))) void*)(g0_ + 64 * 2048),            \
            (__attribute__((address_space(3))) void*)(l0_ + 8192), 16, 0, 0);            \
    } while (0)

    const char* rA0 = (const char*)&As[0][wm][0] + lr * 128;
    const char* rA1 = (const char*)&As[1][wm][0] + lr * 128;
    const char* rB0 = (const char*)&Bs[0][wn >> 1][0] + (wn & 1) * 8192 + lr * 128;
    const char* rB1 = (const char*)&Bs[1][wn >> 1][0] + (wn & 1) * 8192 + lr * 128;

    #define LD_A4(DST, RBASE, MOFFB, SU) do {                                            \
        _Pragma("unroll")                                                                \
        for (int m_ = 0; m_ < 4; ++m_)                                                   \
            DST[m_] = *(const bf16x8*)((RBASE) + (MOFFB) + m_ * 2048 + (SU));            \
    } while (0)
    #define LD_B4(DST, RBASE, SU) do {                                                   \
        _Pragma("unroll")                                                                \
        for (int n_ = 0; n_ < 4; ++n_)                                                   \
            DST[n_] = *(const bf16x8*)((RBASE) + n_ * 2048 + (SU));                      \
    } while (0)
    #define MFMA_QUAD(AF, BF, MO) do {                                                   \
        _Pragma("unroll")                                                                \
        for (int m_ = 0; m_ < 4; ++m_) {                                                 \
            _Pragma("unroll")                                                            \
            for (int n_ = 0; n_ < 4; ++n_)                                               \
                acc[(MO) + m_][n_] = __builtin_amdgcn_mfma_f32_16x16x32_bf16(            \
                    AF[m_], BF[n_], acc[(MO) + m_][n_], 0, 0, 0);                        \
        }                                                                                \
    } while (0)

    bf16x8 a0[4], a1[4], bq0[4], bq1[4];

    STAGE_B(0, 0, 0);  STAGE_B(0, 1, 0);
    STAGE_A(0, 0, 0);  STAGE_A(0, 1, 0);
    STAGE_B(1, 0, 128); STAGE_B(1, 1, 128);
    asm volatile("s_waitcnt vmcnt(4)" ::: "memory");
    __builtin_amdgcn_sched_barrier(0);
    __builtin_amdgcn_s_barrier();

    #pragma unroll 1
    for (int it = 0; it < ITERS; ++it) {
        const bool lastIt = (it == ITERS - 1);
        const int kb1 = (2 * it + 1) * 128;
        const int kb2 = (2 * it + 2) * 128;
        const int kb3 = (2 * it + 3) * 128;

        LD_A4(a0, rA0, 0, su0);
        LD_B4(bq0, rB0, su0);
        STAGE_A(1, 0, kb1);
        PHASE_MID();
        MFMA_QUAD(a0, bq0, 0);
        PHASE_END();

        LD_A4(a1, rA0, 0, su1);
        LD_B4(bq1, rB0, su1);
        STAGE_A(1, 1, kb1);
        PHASE_MID();
        MFMA_QUAD(a1, bq1, 0);
        PHASE_END();

        LD_A4(a0, rA0, 8192, su0);
        if (!lastIt) STAGE_B(0, 0, kb2);
        PHASE_MID();
        MFMA_QUAD(a0, bq0, 4);
        PHASE_END();

        LD_A4(a1, rA0, 8192, su1);
        if (!lastIt) {
            STAGE_B(0, 1, kb2);
            asm volatile("s_waitcnt vmcnt(4)" ::: "memory");
        } else {
            asm volatile("s_waitcnt vmcnt(0)" ::: "memory");
        }
        __builtin_amdgcn_sched_barrier(0);
        PHASE_MID();
        MFMA_QUAD(a1, bq1, 4);
        PHASE_END();

        LD_A4(a0, rA1, 0, su0);
        LD_B4(bq0, rB1, su0);
        if (!lastIt) STAGE_A(0, 0, kb2);
        PHASE_MID();
        MFMA_QUAD(a0, bq0, 0);
        PHASE_END();

        LD_A4(a1, rA1, 0, su1);
        LD_B4(bq1, rB1, su1);
        if (!lastIt) STAGE_A(0, 1, kb2);
        PHASE_MID();
        MFMA_QUAD(a1, bq1, 0);
        PHASE_END();

        LD_A4(a0, rA1, 8192, su0);
        if (!lastIt) STAGE_B(1, 0, kb3);
        PHASE_MID();
        MFMA_QUAD(a0, bq0, 4);
        PHASE_END();

        LD_A4(a1, rA1, 8192, su1);
        if (!lastIt) {
            STAGE_B(1, 1, kb3);
            asm volatile("s_waitcnt vmcnt(4)" ::: "memory");
            __builtin_amdgcn_sched_barrier(0);
        }
        PHASE_MID();
        MFMA_QUAD(a1, bq1, 4);
        PHASE_END();
    }

    int lc[4];
    #pragma unroll
    for (int n = 0; n < 4; ++n)
        lc[n] = labels[colStart + wn * 64 + n * 16 + lr];

    float colAll[4] = {0.f, 0.f, 0.f, 0.f};
    float colPos[4] = {0.f, 0.f, 0.f, 0.f};
    #pragma unroll
    for (int m = 0; m < 8; ++m) {
        #pragma unroll
        for (int e = 0; e < 4; ++e) {
            const int rloc = wm * 128 + m * 16 + q * 4 + e;
            const int gi   = rowStart + rloc;
            const int li   = labels[gi];
            float s_all = 0.f, s_pos = 0.f;
            #pragma unroll
            for (int n = 0; n < 4; ++n) {
                const int cloc = wn * 64 + n * 16 + lr;
                const int gj   = colStart + cloc;
                const float v  = __expf(acc[m][n][e] * invT);
                const bool same = (lc[n] == li);
                s_all += v;
                if (same && gi != gj) s_pos += v;
                if (!isDiag) {
                    colAll[n] += v;
                    if (same) colPos[n] += v;
                }
            }
            #pragma unroll
            for (int off = 1; off < 16; off <<= 1) {
                s_all += __shfl_xor(s_all, off, 64);
                s_pos += __shfl_xor(s_pos, off, 64);
            }
            if (lr == 0) {
                atomicAdd(&sumExp[gi], s_all);
                atomicAdd(&posSum[gi], s_pos);
            }
        }
    }
    if (!isDiag) {
        #pragma unroll
        for (int n = 0; n < 4; ++n) {
            float a = colAll[n], p = colPos[n];
            a += __shfl_xor(a, 16, 64);  a += __shfl_xor(a, 32, 64);
            p += __shfl_xor(p, 16, 64);  p += __shfl_xor(p, 32, 64);
            if (q == 0) {
                const int gj = colStart + wn * 64 + n * 16 + lr;
                atomicAdd(&sumExp[gj], a);
                atomicAdd(&posSum[gj], p);
            }
        }
    }
    }  // end full path

    // =======================================================================
    // Merged finalize: last block to finish reduces loss = mean(log(se/ps)).
    // Fence -> barrier -> tid0 increments device counter; the 576th block
    // re-reads via agent-scope atomic loads (coherent across XCD L2s).
    // =======================================================================
    __threadfence();
    __syncthreads();
    int* lastFlag = (int*)&As[0][0][0];          // reuse LDS (all LDS use done)
    float* redf   = (float*)&As[0][0][64];
    if (tid == 0) *lastFlag = (atomicAdd(cnt, 1) == NBLK - 1) ? 1 : 0;
    __syncthreads();
    if (*lastFlag) {
        float s = 0.f;
        #pragma unroll
        for (int i = tid; i < N; i += 512) {
            const float se = __hip_atomic_load(&sumExp[i], __ATOMIC_RELAXED,
                                               __HIP_MEMORY_SCOPE_AGENT);
            const float ps = __hip_atomic_load(&posSum[i], __ATOMIC_RELAXED,
                                               __HIP_MEMORY_SCOPE_AGENT);
            s += __logf(se / ps);
        }
        #pragma unroll
        for (int off = 32; off >= 1; off >>= 1) s += __shfl_xor(s, off, 64);
        if (lane == 0) redf[wave] = s;
        __syncthreads();
        if (tid == 0) {
            float t = 0.f;
            #pragma unroll
            for (int i = 0; i < 8; ++i) t += redf[i];
            out[0] = t / (float)N;
        }
    }
}

extern "C" void kernel_launch(void* const* d_in, const int* in_sizes, int n_in,
                              void* d_out, int out_size, void* d_ws, size_t ws_size,
                              hipStream_t stream) {
    const float* emb    = (const float*)d_in[0];
    const int*   labels = (const int*)d_in[1];
    float* out = (float*)d_out;

    // ws layout: [sumExp: N floats][posSum: N floats][cnt + pad: 16B][EN: N*D bf16]
    float*  sumExp = (float*)d_ws;
    float*  posSum = sumExp + N;
    int*    cnt    = (int*)((char*)d_ws + (size_t)2 * N * sizeof(float));
    bf16_t* EN     = (bf16_t*)((char*)d_ws + (size_t)2 * N * sizeof(float) + 16);

    norm_cast<<<N / 4, 256, 0, stream>>>(emb, EN, sumExp, posSum, cnt);

    gemm_fused<<<NBLK, 512, 0, stream>>>(EN, labels, sumExp, posSum, out, cnt);
}

// Round 11
// 209.490 us; speedup vs baseline: 1.4758x; 1.4758x over previous
//
#include <hip/hip_runtime.h>
#include <hip/hip_bf16.h>
#include <math.h>

#define N 8192
#define D 1024
#define BM 256
#define BK 64
#define NQUART 64                       // 16 tiles (ti=31, tj=0..15) x 4 quadrants
#define NFULL 512                       // 528 - 16 quartered tiles
#define NBLK (NQUART + NFULL)           // 576
#define ITERS 8                         // full path: 16 K-tiles / 2 per iter

typedef __bf16 bf16_t;
typedef bf16_t bf16x4 __attribute__((ext_vector_type(4)));
typedef bf16_t bf16x8 __attribute__((ext_vector_type(8)));
typedef float f32x4 __attribute__((ext_vector_type(4)));

// ---------------------------------------------------------------------------
// Kernel 1: L2-normalize each row, cast to bf16. Wave-per-row. Also zeroes
// sumExp/posSum (replaces the memset dispatch).
// ---------------------------------------------------------------------------
__global__ __launch_bounds__(256) void norm_cast(const float* __restrict__ in,
                                                 bf16_t* __restrict__ out,
                                                 float* __restrict__ sumExp,
                                                 float* __restrict__ posSum) {
    const int wave = threadIdx.x >> 6, lane = threadIdx.x & 63;
    const int row  = blockIdx.x * 4 + wave;
    const float4* src = (const float4*)(in + (size_t)row * D);
    float4 v[4];
    float ss = 0.f;
    #pragma unroll
    for (int i = 0; i < 4; ++i) {
        v[i] = src[lane + 64 * i];
        ss += v[i].x * v[i].x + v[i].y * v[i].y + v[i].z * v[i].z + v[i].w * v[i].w;
    }
    #pragma unroll
    for (int off = 32; off >= 1; off >>= 1) ss += __shfl_xor(ss, off, 64);
    const float scale = 1.0f / fmaxf(sqrtf(ss), 1e-12f);
    bf16x4* dst = (bf16x4*)(out + (size_t)row * D);
    #pragma unroll
    for (int i = 0; i < 4; ++i) {
        bf16x4 o;
        o[0] = (bf16_t)(v[i].x * scale);
        o[1] = (bf16_t)(v[i].y * scale);
        o[2] = (bf16_t)(v[i].z * scale);
        o[3] = (bf16_t)(v[i].w * scale);
        dst[lane + 64 * i] = o;
    }
    if (lane == 0) { sumExp[row] = 0.f; posSum[row] = 0.f; }
}

// ---------------------------------------------------------------------------
// Kernel 2: fused symmetric  C = E·E^T / T -> exp -> masked row+col sums.
// R11 = R9 (best: 206.7 us total) + quarter path rebuilt on a 3-slot LDS ring
// with one counted vmcnt(4) per K-step (R10's ring, isolated from R10's
// regressive per-block __threadfence finalize, which is reverted).
// Full 256^2 8-phase path byte-identical to R9.
// ---------------------------------------------------------------------------
__global__ __launch_bounds__(512, 2) void gemm_fused(const bf16_t* __restrict__ E,
                                                     const int* __restrict__ labels,
                                                     float* __restrict__ sumExp,
                                                     float* __restrict__ posSum) {
    __shared__ bf16_t As[2][2][128 * 64];   // 64 KB (quarter path: 3-slot ring)
    __shared__ bf16_t Bs[2][2][128 * 64];   // 64 KB  (total 131072 B)

    const int tid  = threadIdx.x;
    const int wave = tid >> 6;
    const int lane = tid & 63;
    const int lr   = lane & 15;
    const int q    = lane >> 4;
    const float invT = 1.0f / 0.07f;

    // swizzled frag-read units (identical formula both paths; 128B LDS rows)
    const int su0 = ((0 + q) ^ (lane & 7)) * 16;     // k = 0
    const int su1 = ((4 + q) ^ (lane & 7)) * 16;     // k = 1

    #define PHASE_MID() do {                                                             \
        __builtin_amdgcn_s_barrier();                                                    \
        asm volatile("s_waitcnt lgkmcnt(0)");                                            \
        __builtin_amdgcn_sched_barrier(0);                                               \
        __builtin_amdgcn_s_setprio(1);                                                   \
    } while (0)
    #define PHASE_END() do {                                                             \
        __builtin_amdgcn_s_setprio(0);                                                   \
        __builtin_amdgcn_s_barrier();                                                    \
    } while (0)

    if (blockIdx.x < NQUART) {
        // ===================================================================
        // QUARTER PATH: 128x128 tile, full K. 3-slot ring (16 KB/slot/operand)
        // carved from As/Bs; stage 2 K-tiles ahead, one counted vmcnt(4) per
        // K-step. All quarters strictly below the diagonal.
        // ===================================================================
        const int qb = ((int)blockIdx.x & 7) * 8 + ((int)blockIdx.x >> 3);
        const int p  = qb >> 2, qd = qb & 3;
        const int rowStart = 31 * BM + (qd >> 1) * 128;
        const int colStart = p * BM + (qd & 1) * 128;
        const int wm2 = wave >> 2;      // 0..1 : 64-row half
        const int wn2 = wave & 3;       // 0..3 : 32-col strip
        char* Aflat = (char*)&As[0][0][0];
        char* Bflat = (char*)&Bs[0][0][0];

        f32x4 acc[4][2];
        #pragma unroll
        for (int m = 0; m < 4; ++m) { acc[m][0] = {0,0,0,0}; acc[m][1] = {0,0,0,0}; }

        const int r0  = tid >> 3;                    // 0..63
        const int lu0 = (tid & 7) ^ (r0 & 7);
        const char* gA = (const char*)(E + (size_t)rowStart * D) + (size_t)r0 * (D * 2) + lu0 * 16;
        const char* gB = (const char*)(E + (size_t)colStart * D) + (size_t)r0 * (D * 2) + lu0 * 16;

        #define QSTAGE(slot, kb) do {                                                    \
            const char* ga_ = gA + (kb);                                                 \
            const char* gb_ = gB + (kb);                                                 \
            char* la_ = Aflat + (slot) * 16384 + wave * 1024;                            \
            char* lb_ = Bflat + (slot) * 16384 + wave * 1024;                            \
            __builtin_amdgcn_global_load_lds((const __attribute__((address_space(1))) void*)ga_, \
                (__attribute__((address_space(3))) void*)la_, 16, 0, 0);                 \
            __builtin_amdgcn_global_load_lds(                                            \
                (const __attribute__((address_space(1))) void*)(ga_ + 64 * 2048),        \
                (__attribute__((address_space(3))) void*)(la_ + 8192), 16, 0, 0);        \
            __builtin_amdgcn_global_load_lds((const __attribute__((address_space(1))) void*)gb_, \
                (__attribute__((address_space(3))) void*)lb_, 16, 0, 0);                 \
            __builtin_amdgcn_global_load_lds(                                            \
                (const __attribute__((address_space(1))) void*)(gb_ + 64 * 2048),        \
                (__attribute__((address_space(3))) void*)(lb_ + 8192), 16, 0, 0);        \
        } while (0)

        bf16x8 qa[4], qbf[2];
        #define QLD(SU, slot) do {                                                       \
            const char* aB_ = Aflat + (slot) * 16384 + (wm2 * 64 + lr) * 128 + (SU);     \
            const char* bB_ = Bflat + (slot) * 16384 + (wn2 * 32 + lr) * 128 + (SU);     \
            _Pragma("unroll")                                                            \
            for (int m_ = 0; m_ < 4; ++m_)                                               \
                qa[m_] = *(const bf16x8*)(aB_ + m_ * 2048);                              \
            qbf[0] = *(const bf16x8*)(bB_);                                              \
            qbf[1] = *(const bf16x8*)(bB_ + 2048);                                       \
        } while (0)
        #define QMFMA() do {                                                             \
            _Pragma("unroll")                                                            \
            for (int m_ = 0; m_ < 4; ++m_) {                                             \
                _Pragma("unroll")                                                        \
                for (int n_ = 0; n_ < 2; ++n_)                                           \
                    acc[m_][n_] = __builtin_amdgcn_mfma_f32_16x16x32_bf16(               \
                        qa[m_], qbf[n_], acc[m_][n_], 0, 0, 0);                          \
            }                                                                            \
        } while (0)

        // prologue: stage K-tiles 0,1 (8 gloads); vmcnt(4) -> tile 0 landed,
        // tile 1 (4 loads) in flight.
        QSTAGE(0, 0);
        QSTAGE(1, 128);
        asm volatile("s_waitcnt vmcnt(4)" ::: "memory");
        __builtin_amdgcn_sched_barrier(0);
        __builtin_amdgcn_s_barrier();

        #pragma unroll 1
        for (int it = 0; it < 16; ++it) {
            const int slot = it % 3;
            // ph1: k0 frags | stage tile it+2 into slot (it+2)%3
            //   (that slot was read in iter it-1; reads fenced by its barrier)
            QLD(su0, slot);
            if (it < 14) QSTAGE((it + 2) % 3, (it + 2) * 128);
            PHASE_MID();
            QMFMA();
            PHASE_END();
            // ph2: k1 frags | counted wait: drain tile it+1 (oldest 4),
            //   keep tile it+2 in flight (a full K-step of slack)
            QLD(su1, slot);
            if (it < 14) asm volatile("s_waitcnt vmcnt(4)" ::: "memory");
            else         asm volatile("s_waitcnt vmcnt(0)" ::: "memory");
            __builtin_amdgcn_sched_barrier(0);
            PHASE_MID();
            QMFMA();
            PHASE_END();
        }

        // epilogue (always off-diagonal, gi != gj guaranteed)
        int lc[2];
        lc[0] = labels[colStart + wn2 * 32 + lr];
        lc[1] = labels[colStart + wn2 * 32 + 16 + lr];
        float colAll[2] = {0.f, 0.f}, colPos[2] = {0.f, 0.f};
        #pragma unroll
        for (int m = 0; m < 4; ++m) {
            #pragma unroll
            for (int e = 0; e < 4; ++e) {
                const int gi = rowStart + wm2 * 64 + m * 16 + q * 4 + e;
                const int li = labels[gi];
                float s_all = 0.f, s_pos = 0.f;
                #pragma unroll
                for (int n = 0; n < 2; ++n) {
                    const float v = __expf(acc[m][n][e] * invT);
                    const bool same = (lc[n] == li);
                    s_all += v;
                    if (same) s_pos += v;
                    colAll[n] += v;
                    if (same) colPos[n] += v;
                }
                #pragma unroll
                for (int off = 1; off < 16; off <<= 1) {
                    s_all += __shfl_xor(s_all, off, 64);
                    s_pos += __shfl_xor(s_pos, off, 64);
                }
                if (lr == 0) {
                    atomicAdd(&sumExp[gi], s_all);
                    atomicAdd(&posSum[gi], s_pos);
                }
            }
        }
        #pragma unroll
        for (int n = 0; n < 2; ++n) {
            float a = colAll[n], pp = colPos[n];
            a += __shfl_xor(a, 16, 64);  a += __shfl_xor(a, 32, 64);
            pp += __shfl_xor(pp, 16, 64); pp += __shfl_xor(pp, 32, 64);
            if (q == 0) {
                const int gj = colStart + wn2 * 32 + n * 16 + lr;
                atomicAdd(&sumExp[gj], a);
                atomicAdd(&posSum[gj], pp);
            }
        }
        return;
    }

    // =======================================================================
    // FULL PATH: R2's verified 256^2 / BK=64 / 8-phase kernel, unchanged.
    // =======================================================================
    const int f0 = (int)blockIdx.x - NQUART;
    const int f  = (f0 & 7) * (NFULL / 8) + (f0 >> 3);     // XCD swizzle, 512%8==0
    const int b  = (f < 496) ? f : f + 16;                 // skip tiles 496..511

    int ti = (int)((sqrtf(8.0f * (float)b + 1.0f) - 1.0f) * 0.5f);
    while ((ti + 1) * (ti + 2) / 2 <= b) ++ti;
    while (ti * (ti + 1) / 2 > b) --ti;
    const int tj = b - ti * (ti + 1) / 2;
    const bool isDiag = (ti == tj);

    const int wm   = wave >> 2;     // 0..1 : row half
    const int wn   = wave & 3;      // 0..3 : 64-col strip
    const int rowStart = ti * BM;
    const int colStart = tj * BM;

    f32x4 acc[8][4];
    #pragma unroll
    for (int m = 0; m < 8; ++m)
        #pragma unroll
        for (int n = 0; n < 4; ++n) acc[m][n] = {0.f, 0.f, 0.f, 0.f};

    const int r0  = tid >> 3;                    // 0..63 (second load adds 64 rows)
    const int lu0 = (tid & 7) ^ (r0 & 7);
    const char* gA = (const char*)(E + (size_t)rowStart * D) + (size_t)r0 * (D * 2) + lu0 * 16;
    const char* gB = (const char*)(E + (size_t)colStart * D) + (size_t)r0 * (D * 2) + lu0 * 16;

    #define STAGE_A(buf, h, kb) do {                                                     \
        const char* g0_ = gA + (size_t)(h) * (128 * 2048) + (kb);                        \
        char* l0_ = (char*)&As[buf][h][0] + wave * 1024;                                 \
        __builtin_amdgcn_global_load_lds((const __attribute__((address_space(1))) void*)g0_, \
            (__attribute__((address_space(3))) void*)l0_, 16, 0, 0);                     \
        __builtin_amdgcn_global_load_lds(                                                \
            (const __attribute__((address_space(1))) void*)(g0_ + 64 * 2048),            \
            (__attribute__((address_space(3))) void*)(l0_ + 8192), 16, 0, 0);            \
    } while (0)
    #define STAGE_B(buf, h, kb) do {                                                     \
        const char* g0_ = gB + (size_t)(h) * (128 * 2048) + (kb);                        \
        char* l0_ = (char*)&Bs[buf][h][0] + wave * 1024;                                 \
        __builtin_amdgcn_global_load_lds((const __attribute__((address_space(1))) void*)g0_, \
            (__attribute__((address_space(3))) void*)l0_, 16, 0, 0);                     \
        __builtin_amdgcn_global_load_lds(                                                \
            (const __attribute__((address_space(1))) void*)(g0_ + 64 * 2048),            \
            (__attribute__((address_space(3))) void*)(l0_ + 8192), 16, 0, 0);            \
    } while (0)

    const char* rA0 = (const char*)&As[0][wm][0] + lr * 128;
    const char* rA1 = (const char*)&As[1][wm][0] + lr * 128;
    const char* rB0 = (const char*)&Bs[0][wn >> 1][0] + (wn & 1) * 8192 + lr * 128;
    const char* rB1 = (const char*)&Bs[1][wn >> 1][0] + (wn & 1) * 8192 + lr * 128;

    #define LD_A4(DST, RBASE, MOFFB, SU) do {                                            \
        _Pragma("unroll")                                                                \
        for (int m_ = 0; m_ < 4; ++m_)                                                   \
            DST[m_] = *(const bf16x8*)((RBASE) + (MOFFB) + m_ * 2048 + (SU));            \
    } while (0)
    #define LD_B4(DST, RBASE, SU) do {                                                   \
        _Pragma("unroll")                                                                \
        for (int n_ = 0; n_ < 4; ++n_)                                                   \
            DST[n_] = *(const bf16x8*)((RBASE) + n_ * 2048 + (SU));                      \
    } while (0)
    #define MFMA_QUAD(AF, BF, MO) do {                                                   \
        _Pragma("unroll")                                                                \
        for (int m_ = 0; m_ < 4; ++m_) {                                                 \
            _Pragma("unroll")                                                            \
            for (int n_ = 0; n_ < 4; ++n_)                                               \
                acc[(MO) + m_][n_] = __builtin_amdgcn_mfma_f32_16x16x32_bf16(            \
                    AF[m_], BF[n_], acc[(MO) + m_][n_], 0, 0, 0);                        \
        }                                                                                \
    } while (0)

    bf16x8 a0[4], a1[4], bq0[4], bq1[4];

    STAGE_B(0, 0, 0);  STAGE_B(0, 1, 0);
    STAGE_A(0, 0, 0);  STAGE_A(0, 1, 0);
    STAGE_B(1, 0, 128); STAGE_B(1, 1, 128);
    asm volatile("s_waitcnt vmcnt(4)" ::: "memory");
    __builtin_amdgcn_sched_barrier(0);
    __builtin_amdgcn_s_barrier();

    #pragma unroll 1
    for (int it = 0; it < ITERS; ++it) {
        const bool lastIt = (it == ITERS - 1);
        const int kb1 = (2 * it + 1) * 128;
        const int kb2 = (2 * it + 2) * 128;
        const int kb3 = (2 * it + 3) * 128;

        LD_A4(a0, rA0, 0, su0);
        LD_B4(bq0, rB0, su0);
        STAGE_A(1, 0, kb1);
        PHASE_MID();
        MFMA_QUAD(a0, bq0, 0);
        PHASE_END();

        LD_A4(a1, rA0, 0, su1);
        LD_B4(bq1, rB0, su1);
        STAGE_A(1, 1, kb1);
        PHASE_MID();
        MFMA_QUAD(a1, bq1, 0);
        PHASE_END();

        LD_A4(a0, rA0, 8192, su0);
        if (!lastIt) STAGE_B(0, 0, kb2);
        PHASE_MID();
        MFMA_QUAD(a0, bq0, 4);
        PHASE_END();

        LD_A4(a1, rA0, 8192, su1);
        if (!lastIt) {
            STAGE_B(0, 1, kb2);
            asm volatile("s_waitcnt vmcnt(4)" ::: "memory");
        } else {
            asm volatile("s_waitcnt vmcnt(0)" ::: "memory");
        }
        __builtin_amdgcn_sched_barrier(0);
        PHASE_MID();
        MFMA_QUAD(a1, bq1, 4);
        PHASE_END();

        LD_A4(a0, rA1, 0, su0);
        LD_B4(bq0, rB1, su0);
        if (!lastIt) STAGE_A(0, 0, kb2);
        PHASE_MID();
        MFMA_QUAD(a0, bq0, 0);
        PHASE_END();

        LD_A4(a1, rA1, 0, su1);
        LD_B4(bq1, rB1, su1);
        if (!lastIt) STAGE_A(0, 1, kb2);
        PHASE_MID();
        MFMA_QUAD(a1, bq1, 0);
        PHASE_END();

        LD_A4(a0, rA1, 8192, su0);
        if (!lastIt) STAGE_B(1, 0, kb3);
        PHASE_MID();
        MFMA_QUAD(a0, bq0, 4);
        PHASE_END();

        LD_A4(a1, rA1, 8192, su1);
        if (!lastIt) {
            STAGE_B(1, 1, kb3);
            asm volatile("s_waitcnt vmcnt(4)" ::: "memory");
            __builtin_amdgcn_sched_barrier(0);
        }
        PHASE_MID();
        MFMA_QUAD(a1, bq1, 4);
        PHASE_END();
    }

    int lc[4];
    #pragma unroll
    for (int n = 0; n < 4; ++n)
        lc[n] = labels[colStart + wn * 64 + n * 16 + lr];

    float colAll[4] = {0.f, 0.f, 0.f, 0.f};
    float colPos[4] = {0.f, 0.f, 0.f, 0.f};
    #pragma unroll
    for (int m = 0; m < 8; ++m) {
        #pragma unroll
        for (int e = 0; e < 4; ++e) {
            const int rloc = wm * 128 + m * 16 + q * 4 + e;
            const int gi   = rowStart + rloc;
            const int li   = labels[gi];
            float s_all = 0.f, s_pos = 0.f;
            #pragma unroll
            for (int n = 0; n < 4; ++n) {
                const int cloc = wn * 64 + n * 16 + lr;
                const int gj   = colStart + cloc;
                const float v  = __expf(acc[m][n][e] * invT);
                const bool same = (lc[n] == li);
                s_all += v;
                if (same && gi != gj) s_pos += v;
                if (!isDiag) {
                    colAll[n] += v;
                    if (same) colPos[n] += v;
                }
            }
            #pragma unroll
            for (int off = 1; off < 16; off <<= 1) {
                s_all += __shfl_xor(s_all, off, 64);
                s_pos += __shfl_xor(s_pos, off, 64);
            }
            if (lr == 0) {
                atomicAdd(&sumExp[gi], s_all);
                atomicAdd(&posSum[gi], s_pos);
            }
        }
    }
    if (!isDiag) {
        #pragma unroll
        for (int n = 0; n < 4; ++n) {
            float a = colAll[n], p = colPos[n];
            a += __shfl_xor(a, 16, 64);  a += __shfl_xor(a, 32, 64);
            p += __shfl_xor(p, 16, 64);  p += __shfl_xor(p, 32, 64);
            if (q == 0) {
                const int gj = colStart + wn * 64 + n * 16 + lr;
                atomicAdd(&sumExp[gj], a);
                atomicAdd(&posSum[gj], p);
            }
        }
    }
}

// ---------------------------------------------------------------------------
// Kernel 3: loss_i = log(sumExp_i / posSum_i); out = mean(loss).
// ---------------------------------------------------------------------------
__global__ __launch_bounds__(1024) void finalize(const float* __restrict__ sumExp,
                                                 const float* __restrict__ posSum,
                                                 float* __restrict__ out) {
    const int tid = threadIdx.x;
    float s = 0.f;
    #pragma unroll
    for (int i = tid; i < N; i += 1024)
        s += __logf(sumExp[i] / posSum[i]);
    #pragma unroll
    for (int off = 32; off >= 1; off >>= 1) s += __shfl_xor(s, off, 64);
    __shared__ float red[16];
    if ((tid & 63) == 0) red[tid >> 6] = s;
    __syncthreads();
    if (tid == 0) {
        float t = 0.f;
        #pragma unroll
        for (int i = 0; i < 16; ++i) t += red[i];
        out[0] = t / (float)N;
    }
}

extern "C" void kernel_launch(void* const* d_in, const int* in_sizes, int n_in,
                              void* d_out, int out_size, void* d_ws, size_t ws_size,
                              hipStream_t stream) {
    const float* emb    = (const float*)d_in[0];
    const int*   labels = (const int*)d_in[1];
    float* out = (float*)d_out;

    // ws layout: [sumExp: N floats][posSum: N floats][EN: N*D bf16]
    float*  sumExp = (float*)d_ws;
    float*  posSum = sumExp + N;
    bf16_t* EN     = (bf16_t*)((char*)d_ws + (size_t)2 * N * sizeof(float));

    norm_cast<<<N / 4, 256, 0, stream>>>(emb, EN, sumExp, posSum);

    gemm_fused<<<NBLK, 512, 0, stream>>>(EN, labels, sumExp, posSum);

    finalize<<<1, 1024, 0, stream>>>(sumExp, posSum, out);
}

// Round 12
// 208.178 us; speedup vs baseline: 1.4851x; 1.0063x over previous
//
#include <hip/hip_runtime.h>
#include <hip/hip_bf16.h>
#include <math.h>

#define N 8192
#define D 1024
#define BM 256
#define BK 64
#define NQUART 64                       // 16 tiles (ti=31, tj=0..15) x 4 quadrants
#define NFULL 512                       // 528 - 16 quartered tiles
#define NBLK (NQUART + NFULL)           // 576: fulls first (0..511), quarters last
#define ITERS 8                         // full path: 16 K-tiles / 2 per iter

typedef __bf16 bf16_t;
typedef bf16_t bf16x4 __attribute__((ext_vector_type(4)));
typedef bf16_t bf16x8 __attribute__((ext_vector_type(8)));
typedef float f32x4 __attribute__((ext_vector_type(4)));

// ---------------------------------------------------------------------------
// Kernel 1: L2-normalize each row, cast to bf16. Wave-per-row. Also zeroes
// sumExp/posSum (replaces the memset dispatch).
// ---------------------------------------------------------------------------
__global__ __launch_bounds__(256) void norm_cast(const float* __restrict__ in,
                                                 bf16_t* __restrict__ out,
                                                 float* __restrict__ sumExp,
                                                 float* __restrict__ posSum) {
    const int wave = threadIdx.x >> 6, lane = threadIdx.x & 63;
    const int row  = blockIdx.x * 4 + wave;
    const float4* src = (const float4*)(in + (size_t)row * D);
    float4 v[4];
    float ss = 0.f;
    #pragma unroll
    for (int i = 0; i < 4; ++i) {
        v[i] = src[lane + 64 * i];
        ss += v[i].x * v[i].x + v[i].y * v[i].y + v[i].z * v[i].z + v[i].w * v[i].w;
    }
    #pragma unroll
    for (int off = 32; off >= 1; off >>= 1) ss += __shfl_xor(ss, off, 64);
    const float scale = 1.0f / fmaxf(sqrtf(ss), 1e-12f);
    bf16x4* dst = (bf16x4*)(out + (size_t)row * D);
    #pragma unroll
    for (int i = 0; i < 4; ++i) {
        bf16x4 o;
        o[0] = (bf16_t)(v[i].x * scale);
        o[1] = (bf16_t)(v[i].y * scale);
        o[2] = (bf16_t)(v[i].z * scale);
        o[3] = (bf16_t)(v[i].w * scale);
        dst[lane + 64 * i] = o;
    }
    if (lane == 0) { sumExp[row] = 0.f; posSum[row] = 0.f; }
}

// ---------------------------------------------------------------------------
// Kernel 2: fused symmetric  C = E·E^T / T -> exp -> masked row+col sums.
// R12 = R9/R11 full path (unchanged, blockIdx 0..511, LPT-first) + quarter
// path rebuilt with BK=128 double-buffer: 8 K-steps, ONE barrier + ONE
// vmcnt(0) per step (vs 32 stall-bound phases) -> tail cost Xq ~41 -> ~12 us.
// ---------------------------------------------------------------------------
__global__ __launch_bounds__(512, 2) void gemm_fused(const bf16_t* __restrict__ E,
                                                     const int* __restrict__ labels,
                                                     float* __restrict__ sumExp,
                                                     float* __restrict__ posSum) {
    __shared__ bf16_t As[2][2][128 * 64];   // 64 KB (quarter: 2 x 32 KB BK=128 bufs)
    __shared__ bf16_t Bs[2][2][128 * 64];   // 64 KB  (total 131072 B)

    const int tid  = threadIdx.x;
    const int wave = tid >> 6;
    const int lane = tid & 63;
    const int lr   = lane & 15;
    const int q    = lane >> 4;
    const float invT = 1.0f / 0.07f;

    // full-path swizzled frag-read units (128B LDS rows)
    const int su0 = ((0 + q) ^ (lane & 7)) * 16;     // k = 0
    const int su1 = ((4 + q) ^ (lane & 7)) * 16;     // k = 1

    #define PHASE_MID() do {                                                             \
        __builtin_amdgcn_s_barrier();                                                    \
        asm volatile("s_waitcnt lgkmcnt(0)");                                            \
        __builtin_amdgcn_sched_barrier(0);                                               \
        __builtin_amdgcn_s_setprio(1);                                                   \
    } while (0)
    #define PHASE_END() do {                                                             \
        __builtin_amdgcn_s_setprio(0);                                                   \
        __builtin_amdgcn_s_barrier();                                                    \
    } while (0)

    if (blockIdx.x >= NFULL) {
        // ===================================================================
        // QUARTER PATH (tail): 128x128 tile, BK=128, double-buffered.
        // 8 K-steps; per step: stage next buf (8 gloads) | 4 k-chunks of
        // {6 ds_read_b128 + 8 MFMA} | vmcnt(0) | barrier.
        // LDS rows are 256 B (16 x 16B units); swizzle: phys unit =
        // logical ^ (row&7) on low 3 bits; staging inverse-permutes the
        // global source (linear LDS dest). All quarters strictly
        // below-diagonal (rowStart >= 7936 > colStart+127).
        // ===================================================================
        const int qb = (int)blockIdx.x - NFULL;     // 0..63
        const int p  = qb >> 2, qd = qb & 3;
        const int rowStart = 31 * BM + (qd >> 1) * 128;
        const int colStart = p * BM + (qd & 1) * 128;
        const int wm2 = wave >> 2;      // 0..1 : 64-row half
        const int wn2 = wave & 3;       // 0..3 : 32-col strip
        char* Aflat = (char*)&As[0][0][0];
        char* Bflat = (char*)&Bs[0][0][0];

        f32x4 acc[4][2];
        #pragma unroll
        for (int m = 0; m < 4; ++m) { acc[m][0] = {0,0,0,0}; acc[m][1] = {0,0,0,0}; }

        // staging geometry: per gload 512 thr x 16B = 32 rows x 256 B.
        // phys unit u = tid&15 -> logical u ^ (row&7); row-in-chunk = tid>>4.
        const int r0 = tid >> 4;                     // 0..31
        const int lu = (tid & 15) ^ (r0 & 7);
        const char* gA = (const char*)(E + (size_t)rowStart * D) + (size_t)r0 * 2048 + lu * 16;
        const char* gB = (const char*)(E + (size_t)colStart * D) + (size_t)r0 * 2048 + lu * 16;

        #define Q128STAGE(bi, t) do {                                                    \
            const char* ga_ = gA + (t) * 256;                                            \
            const char* gb_ = gB + (t) * 256;                                            \
            char* la_ = Aflat + (bi) * 32768 + wave * 1024;                              \
            char* lb_ = Bflat + (bi) * 32768 + wave * 1024;                              \
            _Pragma("unroll")                                                            \
            for (int g_ = 0; g_ < 4; ++g_) {                                             \
                __builtin_amdgcn_global_load_lds(                                        \
                    (const __attribute__((address_space(1))) void*)(ga_ + g_ * 32 * 2048), \
                    (__attribute__((address_space(3))) void*)(la_ + g_ * 8192), 16, 0, 0); \
                __builtin_amdgcn_global_load_lds(                                        \
                    (const __attribute__((address_space(1))) void*)(gb_ + g_ * 32 * 2048), \
                    (__attribute__((address_space(3))) void*)(lb_ + g_ * 8192), 16, 0, 0); \
            }                                                                            \
        } while (0)

        // prologue: buf0 = K-tile 0
        Q128STAGE(0, 0);
        asm volatile("s_waitcnt vmcnt(0)" ::: "memory");
        __builtin_amdgcn_sched_barrier(0);
        __builtin_amdgcn_s_barrier();

        #pragma unroll 1
        for (int s = 0; s < 8; ++s) {
            const int buf = s & 1;
            if (s < 7) Q128STAGE(buf ^ 1, s + 1);   // buf^1's reads ended step s-1
            const char* aB = Aflat + buf * 32768 + (wm2 * 64 + lr) * 256;
            const char* bB = Bflat + buf * 32768 + (wn2 * 32 + lr) * 256;
            #pragma unroll
            for (int kc = 0; kc < 4; ++kc) {
                const int su_ = ((kc * 4 + q) ^ (lane & 7)) * 16;
                bf16x8 qa[4], qbv[2];
                #pragma unroll
                for (int m_ = 0; m_ < 4; ++m_)
                    qa[m_] = *(const bf16x8*)(aB + m_ * 4096 + su_);
                qbv[0] = *(const bf16x8*)(bB + su_);
                qbv[1] = *(const bf16x8*)(bB + 4096 + su_);
                #pragma unroll
                for (int m_ = 0; m_ < 4; ++m_) {
                    #pragma unroll
                    for (int n_ = 0; n_ < 2; ++n_)
                        acc[m_][n_] = __builtin_amdgcn_mfma_f32_16x16x32_bf16(
                            qa[m_], qbv[n_], acc[m_][n_], 0, 0, 0);
                }
            }
            asm volatile("s_waitcnt vmcnt(0)" ::: "memory");   // next tile landed
            __builtin_amdgcn_sched_barrier(0);
            __builtin_amdgcn_s_barrier();                      // reads done + staged visible
        }

        // epilogue (always off-diagonal, gi != gj guaranteed)
        int lc[2];
        lc[0] = labels[colStart + wn2 * 32 + lr];
        lc[1] = labels[colStart + wn2 * 32 + 16 + lr];
        float colAll[2] = {0.f, 0.f}, colPos[2] = {0.f, 0.f};
        #pragma unroll
        for (int m = 0; m < 4; ++m) {
            #pragma unroll
            for (int e = 0; e < 4; ++e) {
                const int gi = rowStart + wm2 * 64 + m * 16 + q * 4 + e;
                const int li = labels[gi];
                float s_all = 0.f, s_pos = 0.f;
                #pragma unroll
                for (int n = 0; n < 2; ++n) {
                    const float v = __expf(acc[m][n][e] * invT);
                    const bool same = (lc[n] == li);
                    s_all += v;
                    if (same) s_pos += v;
                    colAll[n] += v;
                    if (same) colPos[n] += v;
                }
                #pragma unroll
                for (int off = 1; off < 16; off <<= 1) {
                    s_all += __shfl_xor(s_all, off, 64);
                    s_pos += __shfl_xor(s_pos, off, 64);
                }
                if (lr == 0) {
                    atomicAdd(&sumExp[gi], s_all);
                    atomicAdd(&posSum[gi], s_pos);
                }
            }
        }
        #pragma unroll
        for (int n = 0; n < 2; ++n) {
            float a = colAll[n], pp = colPos[n];
            a += __shfl_xor(a, 16, 64);  a += __shfl_xor(a, 32, 64);
            pp += __shfl_xor(pp, 16, 64); pp += __shfl_xor(pp, 32, 64);
            if (q == 0) {
                const int gj = colStart + wn2 * 32 + n * 16 + lr;
                atomicAdd(&sumExp[gj], a);
                atomicAdd(&posSum[gj], pp);
            }
        }
        return;
    }

    // =======================================================================
    // FULL PATH: R2's verified 256^2 / BK=64 / 8-phase kernel, unchanged.
    // blockIdx 0..511 (LPT: long blocks first, quarters fill the tail).
    // =======================================================================
    const int f0 = (int)blockIdx.x;
    const int f  = (f0 & 7) * (NFULL / 8) + (f0 >> 3);     // XCD swizzle, 512%8==0
    const int b  = (f < 496) ? f : f + 16;                 // skip tiles 496..511

    int ti = (int)((sqrtf(8.0f * (float)b + 1.0f) - 1.0f) * 0.5f);
    while ((ti + 1) * (ti + 2) / 2 <= b) ++ti;
    while (ti * (ti + 1) / 2 > b) --ti;
    const int tj = b - ti * (ti + 1) / 2;
    const bool isDiag = (ti == tj);

    const int wm   = wave >> 2;     // 0..1 : row half
    const int wn   = wave & 3;      // 0..3 : 64-col strip
    const int rowStart = ti * BM;
    const int colStart = tj * BM;

    f32x4 acc[8][4];
    #pragma unroll
    for (int m = 0; m < 8; ++m)
        #pragma unroll
        for (int n = 0; n < 4; ++n) acc[m][n] = {0.f, 0.f, 0.f, 0.f};

    const int r0  = tid >> 3;                    // 0..63 (second load adds 64 rows)
    const int lu0 = (tid & 7) ^ (r0 & 7);
    const char* gA = (const char*)(E + (size_t)rowStart * D) + (size_t)r0 * (D * 2) + lu0 * 16;
    const char* gB = (const char*)(E + (size_t)colStart * D) + (size_t)r0 * (D * 2) + lu0 * 16;

    #define STAGE_A(buf, h, kb) do {                                                     \
        const char* g0_ = gA + (size_t)(h) * (128 * 2048) + (kb);                        \
        char* l0_ = (char*)&As[buf][h][0] + wave * 1024;                                 \
        __builtin_amdgcn_global_load_lds((const __attribute__((address_space(1))) void*)g0_, \
            (__attribute__((address_space(3))) void*)l0_, 16, 0, 0);                     \
        __builtin_amdgcn_global_load_lds(                                                \
            (const __attribute__((address_space(1))) void*)(g0_ + 64 * 2048),            \
            (__attribute__((address_space(3))) void*)(l0_ + 8192), 16, 0, 0);            \
    } while (0)
    #define STAGE_B(buf, h, kb) do {                                                     \
        const char* g0_ = gB + (size_t)(h) * (128 * 2048) + (kb);                        \
        char* l0_ = (char*)&Bs[buf][h][0] + wave * 1024;                                 \
        __builtin_amdgcn_global_load_lds((const __attribute__((address_space(1))) void*)g0_, \
            (__attribute__((address_space(3))) void*)l0_, 16, 0, 0);                     \
        __builtin_amdgcn_global_load_lds(                                                \
            (const __attribute__((address_space(1))) void*)(g0_ + 64 * 2048),            \
            (__attribute__((address_space(3))) void*)(l0_ + 8192), 16, 0, 0);            \
    } while (0)

    const char* rA0 = (const char*)&As[0][wm][0] + lr * 128;
    const char* rA1 = (const char*)&As[1][wm][0] + lr * 128;
    const char* rB0 = (const char*)&Bs[0][wn >> 1][0] + (wn & 1) * 8192 + lr * 128;
    const char* rB1 = (const char*)&Bs[1][wn >> 1][0] + (wn & 1) * 8192 + lr * 128;

    #define LD_A4(DST, RBASE, MOFFB, SU) do {                                            \
        _Pragma("unroll")                                                                \
        for (int m_ = 0; m_ < 4; ++m_)                                                   \
            DST[m_] = *(const bf16x8*)((RBASE) + (MOFFB) + m_ * 2048 + (SU));            \
    } while (0)
    #define LD_B4(DST, RBASE, SU) do {                                                   \
        _Pragma("unroll")                                                                \
        for (int n_ = 0; n_ < 4; ++n_)                                                   \
            DST[n_] = *(const bf16x8*)((RBASE) + n_ * 2048 + (SU));                      \
    } while (0)
    #define MFMA_QUAD(AF, BF, MO) do {                                                   \
        _Pragma("unroll")                                                                \
        for (int m_ = 0; m_ < 4; ++m_) {                                                 \
            _Pragma("unroll")                                                            \
            for (int n_ = 0; n_ < 4; ++n_)                                               \
                acc[(MO) + m_][n_] = __builtin_amdgcn_mfma_f32_16x16x32_bf16(            \
                    AF[m_], BF[n_], acc[(MO) + m_][n_], 0, 0, 0);                        \
        }                                                                                \
    } while (0)

    bf16x8 a0[4], a1[4], bq0[4], bq1[4];

    STAGE_B(0, 0, 0);  STAGE_B(0, 1, 0);
    STAGE_A(0, 0, 0);  STAGE_A(0, 1, 0);
    STAGE_B(1, 0, 128); STAGE_B(1, 1, 128);
    asm volatile("s_waitcnt vmcnt(4)" ::: "memory");
    __builtin_amdgcn_sched_barrier(0);
    __builtin_amdgcn_s_barrier();

    #pragma unroll 1
    for (int it = 0; it < ITERS; ++it) {
        const bool lastIt = (it == ITERS - 1);
        const int kb1 = (2 * it + 1) * 128;
        const int kb2 = (2 * it + 2) * 128;
        const int kb3 = (2 * it + 3) * 128;

        LD_A4(a0, rA0, 0, su0);
        LD_B4(bq0, rB0, su0);
        STAGE_A(1, 0, kb1);
        PHASE_MID();
        MFMA_QUAD(a0, bq0, 0);
        PHASE_END();

        LD_A4(a1, rA0, 0, su1);
        LD_B4(bq1, rB0, su1);
        STAGE_A(1, 1, kb1);
        PHASE_MID();
        MFMA_QUAD(a1, bq1, 0);
        PHASE_END();

        LD_A4(a0, rA0, 8192, su0);
        if (!lastIt) STAGE_B(0, 0, kb2);
        PHASE_MID();
        MFMA_QUAD(a0, bq0, 4);
        PHASE_END();

        LD_A4(a1, rA0, 8192, su1);
        if (!lastIt) {
            STAGE_B(0, 1, kb2);
            asm volatile("s_waitcnt vmcnt(4)" ::: "memory");
        } else {
            asm volatile("s_waitcnt vmcnt(0)" ::: "memory");
        }
        __builtin_amdgcn_sched_barrier(0);
        PHASE_MID();
        MFMA_QUAD(a1, bq1, 4);
        PHASE_END();

        LD_A4(a0, rA1, 0, su0);
        LD_B4(bq0, rB1, su0);
        if (!lastIt) STAGE_A(0, 0, kb2);
        PHASE_MID();
        MFMA_QUAD(a0, bq0, 0);
        PHASE_END();

        LD_A4(a1, rA1, 0, su1);
        LD_B4(bq1, rB1, su1);
        if (!lastIt) STAGE_A(0, 1, kb2);
        PHASE_MID();
        MFMA_QUAD(a1, bq1, 0);
        PHASE_END();

        LD_A4(a0, rA1, 8192, su0);
        if (!lastIt) STAGE_B(1, 0, kb3);
        PHASE_MID();
        MFMA_QUAD(a0, bq0, 4);
        PHASE_END();

        LD_A4(a1, rA1, 8192, su1);
        if (!lastIt) {
            STAGE_B(1, 1, kb3);
            asm volatile("s_waitcnt vmcnt(4)" ::: "memory");
            __builtin_amdgcn_sched_barrier(0);
        }
        PHASE_MID();
        MFMA_QUAD(a1, bq1, 4);
        PHASE_END();
    }

    int lc[4];
    #pragma unroll
    for (int n = 0; n < 4; ++n)
        lc[n] = labels[colStart + wn * 64 + n * 16 + lr];

    float colAll[4] = {0.f, 0.f, 0.f, 0.f};
    float colPos[4] = {0.f, 0.f, 0.f, 0.f};
    #pragma unroll
    for (int m = 0; m < 8; ++m) {
        #pragma unroll
        for (int e = 0; e < 4; ++e) {
            const int rloc = wm * 128 + m * 16 + q * 4 + e;
            const int gi   = rowStart + rloc;
            const int li   = labels[gi];
            float s_all = 0.f, s_pos = 0.f;
            #pragma unroll
            for (int n = 0; n < 4; ++n) {
                const int cloc = wn * 64 + n * 16 + lr;
                const int gj   = colStart + cloc;
                const float v  = __expf(acc[m][n][e] * invT);
                const bool same = (lc[n] == li);
                s_all += v;
                if (same && gi != gj) s_pos += v;
                if (!isDiag) {
                    colAll[n] += v;
                    if (same) colPos[n] += v;
                }
            }
            #pragma unroll
            for (int off = 1; off < 16; off <<= 1) {
                s_all += __shfl_xor(s_all, off, 64);
                s_pos += __shfl_xor(s_pos, off, 64);
            }
            if (lr == 0) {
                atomicAdd(&sumExp[gi], s_all);
                atomicAdd(&posSum[gi], s_pos);
            }
        }
    }
    if (!isDiag) {
        #pragma unroll
        for (int n = 0; n < 4; ++n) {
            float a = colAll[n], p = colPos[n];
            a += __shfl_xor(a, 16, 64);  a += __shfl_xor(a, 32, 64);
            p += __shfl_xor(p, 16, 64);  p += __shfl_xor(p, 32, 64);
            if (q == 0) {
                const int gj = colStart + wn * 64 + n * 16 + lr;
                atomicAdd(&sumExp[gj], a);
                atomicAdd(&posSum[gj], p);
            }
        }
    }
}

// ---------------------------------------------------------------------------
// Kernel 3: loss_i = log(sumExp_i / posSum_i); out = mean(loss).
// ---------------------------------------------------------------------------
__global__ __launch_bounds__(1024) void finalize(const float* __restrict__ sumExp,
                                                 const float* __restrict__ posSum,
                                                 float* __restrict__ out) {
    const int tid = threadIdx.x;
    float s = 0.f;
    #pragma unroll
    for (int i = tid; i < N; i += 1024)
        s += __logf(sumExp[i] / posSum[i]);
    #pragma unroll
    for (int off = 32; off >= 1; off >>= 1) s += __shfl_xor(s, off, 64);
    __shared__ float red[16];
    if ((tid & 63) == 0) red[tid >> 6] = s;
    __syncthreads();
    if (tid == 0) {
        float t = 0.f;
        #pragma unroll
        for (int i = 0; i < 16; ++i) t += red[i];
        out[0] = t / (float)N;
    }
}

extern "C" void kernel_launch(void* const* d_in, const int* in_sizes, int n_in,
                              void* d_out, int out_size, void* d_ws, size_t ws_size,
                              hipStream_t stream) {
    const float* emb    = (const float*)d_in[0];
    const int*   labels = (const int*)d_in[1];
    float* out = (float*)d_out;

    // ws layout: [sumExp: N floats][posSum: N floats][EN: N*D bf16]
    float*  sumExp = (float*)d_ws;
    float*  posSum = sumExp + N;
    bf16_t* EN     = (bf16_t*)((char*)d_ws + (size_t)2 * N * sizeof(float));

    norm_cast<<<N / 4, 256, 0, stream>>>(emb, EN, sumExp, posSum);

    gemm_fused<<<NBLK, 512, 0, stream>>>(EN, labels, sumExp, posSum);

    finalize<<<1, 1024, 0, stream>>>(sumExp, posSum, out);
}